// Round 5
// baseline (282.673 us; speedup 1.0000x reference)
//
#include <hip/hip_runtime.h>

#define NN 2048      // nodes per batch
#define FF 128       // features per node
#define KK 16        // top-K
#define INF_KEY 0xFFFFFFFFFFFFFFFFull

// native clang vector type — required by __builtin_nontemporal_store
typedef float vfloat4 __attribute__((ext_vector_type(4)));

// ---------- wave64 min-reduce via DPP (VALU pipe, no LDS/permute) ----------
__device__ __forceinline__ unsigned wave_min_u32(unsigned x) {
    int v = (int)x, t;
    t = __builtin_amdgcn_update_dpp(v, v, 0x111, 0xf, 0xf, false); // row_shr:1
    v = ((unsigned)t < (unsigned)v) ? t : v;
    t = __builtin_amdgcn_update_dpp(v, v, 0x112, 0xf, 0xf, false); // row_shr:2
    v = ((unsigned)t < (unsigned)v) ? t : v;
    t = __builtin_amdgcn_update_dpp(v, v, 0x114, 0xf, 0xf, false); // row_shr:4
    v = ((unsigned)t < (unsigned)v) ? t : v;
    t = __builtin_amdgcn_update_dpp(v, v, 0x118, 0xf, 0xf, false); // row_shr:8
    v = ((unsigned)t < (unsigned)v) ? t : v;
    t = __builtin_amdgcn_update_dpp(v, v, 0x142, 0xf, 0xf, false); // row_bcast:15
    v = ((unsigned)t < (unsigned)v) ? t : v;
    t = __builtin_amdgcn_update_dpp(v, v, 0x143, 0xf, 0xf, false); // row_bcast:31
    v = ((unsigned)t < (unsigned)v) ? t : v;
    return (unsigned)__builtin_amdgcn_readlane(v, 63);
}

// Fused: one block = 4 rows of one batch. Inactive rows stream zeros (pure
// BW); active rows build a per-lane sorted top-4 queue of packed (d2,j+1)
// keys in one LDS pass (SoA sx/sy/sz: 2-way bank alias, free), extract the
// global top-16 with 32-bit DPP mins (exact refill covers >4-per-lane), and
// stream the 0/1 row via a 1 KB LDS word table (coalesced 16B stores).
// R5: non-temporal output stores via clang ext_vector_type (268 MB stream,
// never re-read — skip L2 allocate/evict churn). Selection logic identical
// to R3 (absmax 0).
__global__ __launch_bounds__(256) void knn_adj_fused(
    const float* __restrict__ nodes,
    const int*   __restrict__ T_arr,
    const int*   __restrict__ tau_arr,
    float*       __restrict__ adj)
{
    const int b    = blockIdx.x;
    const int i0   = blockIdx.y << 2;
    const int tid  = threadIdx.x;
    const int wave = tid >> 6;
    const int lane = tid & 63;

    const int tau = tau_arr[b];
    float* block_out = adj + ((size_t)b * NN + i0) * NN;

    if (i0 >= tau) {                          // whole block inactive: 32 KB zeros
        const vfloat4 z = {0.f, 0.f, 0.f, 0.f};
        vfloat4* out4 = (vfloat4*)block_out;
        #pragma unroll
        for (int t = 0; t < 8; ++t)
            __builtin_nontemporal_store(z, &out4[tid + (t << 8)]);
        return;
    }

    const int T = T_arr[b];
    const int M = T + tau;                    // src_valid: j < M (<= 2046)

    __shared__ float sx[NN], sy[NN], sz[NN];  // 24 KiB, SoA: conflict-free
    __shared__ unsigned swords[4][64];        // 1 KiB: per-wave column words
    for (int j = tid; j < M; j += 256) {
        const float* p = nodes + ((size_t)b * NN + j) * FF;
        sx[j] = p[0];
        sy[j] = p[1];
        sz[j] = p[2];
    }
    __syncthreads();

    const int i = i0 + wave;
    vfloat4* out4 = (vfloat4*)(block_out + (size_t)wave * NN);

    if (i >= tau) {                           // inactive row in active block
        const vfloat4 z = {0.f, 0.f, 0.f, 0.f};
        #pragma unroll
        for (int t = 0; t < 8; ++t)
            __builtin_nontemporal_store(z, &out4[(t << 6) + lane]);
        return;
    }

    const int g = T + i;                      // sink global index (< M always)
    const float sxv = sx[g], syv = sy[g], szv = sz[g];

    // ---- one-pass build of per-lane sorted top-4 queue ----
    unsigned long long q0 = INF_KEY, q1 = INF_KEY, q2 = INF_KEY, q3 = INF_KEY;
    const int S = (M + 63) >> 6;
    #pragma unroll 4
    for (int s = 0; s < S; ++s) {
        const int j = lane + (s << 6);
        if (j < M) {
            float dx = __fsub_rn(sxv, sx[j]);
            float dy = __fsub_rn(syv, sy[j]);
            float dz = __fsub_rn(szv, sz[j]);
            float d2 = __fadd_rn(__fadd_rn(__fmul_rn(dx, dx), __fmul_rn(dy, dy)),
                                 __fmul_rn(dz, dz));
            unsigned long long key =
                ((unsigned long long)__float_as_uint(d2) << 32) | (unsigned)(j + 1);
            if (key < q3) {
                q3 = key;
                unsigned long long t;
                if (q3 < q2) { t = q2; q2 = q3; q3 = t; }
                if (q2 < q1) { t = q1; q1 = q2; q2 = t; }
                if (q1 < q0) { t = q0; q0 = q1; q1 = t; }
            }
        }
    }

    // ---- 16 extraction rounds: DPP min on head d2 + ballot index resolve ----
    unsigned colmask = 0;                     // this lane's cols [32*lane, +32)
    unsigned long long lastpop = 0;
    for (int k = 0; k < KK; ++k) {
        const unsigned hd = (unsigned)(q0 >> 32);
        const unsigned m  = wave_min_u32(hd);
        if (m == 0xFFFFFFFFu) break;          // all lanes exhausted

        const unsigned long long mask = __ballot(hd == m);
        unsigned jwin;
        if (__popcll(mask) == 1) {            // unique head d2 (common case)
            const int w = __builtin_ctzll(mask);
            jwin = (unsigned)__builtin_amdgcn_readlane((int)(unsigned)q0, w);
        } else {                              // cross-lane d2 tie (rare)
            unsigned jc = (hd == m) ? (unsigned)q0 : 0xFFFFFFFFu;
            jwin = wave_min_u32(jc);
        }
        const int j = (int)jwin - 1;

        if (j < i && (j >> 5) == lane)        // causal + word ownership
            colmask |= 1u << (j & 31);

        if (hd == m && (unsigned)q0 == jwin) {  // pop on the winner lane
            lastpop = ((unsigned long long)m << 32) | jwin;
            q0 = q1; q1 = q2; q2 = q3; q3 = INF_KEY;
            if (q0 == INF_KEY) {              // rare: >4 global hits this lane
                unsigned long long best = INF_KEY;
                for (int s2 = 0; s2 < S; ++s2) {
                    const int jj = lane + (s2 << 6);
                    if (jj < M) {
                        float dx = __fsub_rn(sxv, sx[jj]);
                        float dy = __fsub_rn(syv, sy[jj]);
                        float dz = __fsub_rn(szv, sz[jj]);
                        float d2 = __fadd_rn(
                            __fadd_rn(__fmul_rn(dx, dx), __fmul_rn(dy, dy)),
                            __fmul_rn(dz, dz));
                        unsigned long long kk =
                            ((unsigned long long)__float_as_uint(d2) << 32)
                            | (unsigned)(jj + 1);
                        if (kk > lastpop && kk < best) best = kk;
                    }
                }
                q0 = best;
            }
        }
    }

    // ---- route words through LDS (same wave: no barrier), stream the row ----
    swords[wave][lane] = colmask;
    #pragma unroll
    for (int k = 0; k < 8; ++k) {
        // cols c = 256k + 4*lane .. +3 ; word = 8k + (lane>>3) (broadcast read)
        const unsigned w   = swords[wave][(k << 3) + (lane >> 3)];
        const unsigned nib = (w >> ((lane & 7) << 2)) & 0xFu;
        vfloat4 v;
        v.x = (nib & 1u) ? 1.0f : 0.0f;
        v.y = (nib & 2u) ? 1.0f : 0.0f;
        v.z = (nib & 4u) ? 1.0f : 0.0f;
        v.w = (nib & 8u) ? 1.0f : 0.0f;
        __builtin_nontemporal_store(v, &out4[(k << 6) + lane]);
    }
}

extern "C" void kernel_launch(void* const* d_in, const int* in_sizes, int n_in,
                              void* d_out, int out_size, void* d_ws, size_t ws_size,
                              hipStream_t stream) {
    const float* nodes = (const float*)d_in[0];
    const int*   T     = (const int*)d_in[1];
    const int*   taus  = (const int*)d_in[2];
    float*       adj   = (float*)d_out;
    const int B = in_sizes[1];               // T has B elements (16)

    dim3 grid(B, NN / 4);                    // 16 x 512 blocks, 256 thr each
    knn_adj_fused<<<grid, dim3(256), 0, stream>>>(nodes, T, taus, adj);
}